// Round 2
// baseline (176.826 us; speedup 1.0000x reference)
//
#include <hip/hip_runtime.h>

// LongformerAttention MI355X — Round 12.
// gemm_qkv rewritten as ONE 4096x3072x1024 GEMM (Wq/Wk/Wv contiguous in ws)
// with the 8-phase counted-vmcnt schedule (T3+T4+T5): BM=256 BN=192 BK=64,
// 256 blocks (1/CU), 512 thr (2Mx4N waves), LDS 112 KB dbuf. Per K-tile:
// 4 phases (M-half x {j01, j2}); stage-chunk issue pinned one phase after
// that region's last ds_read; vmcnt(7) once per K-tile boundary (never 0 in
// steady state). Epilogue resolves Q/K/V per 16-col frag (wave-uniform).
// attn/cvt/gemm_wo/combine unchanged from Round 11.

#define B_   2
#define S_   2048
#define DM   1024
#define H_   16
#define NG   204                     // max(1, int(S*0.1))
#define BS_  4096                    // B_*S_
#define SCL2 0.1803368801111204f     // (1/sqrt(64)) * log2(e)  — folded into Q
#define NEGF -3.0e38f

typedef unsigned short u16;
typedef unsigned int   u32;
typedef __attribute__((ext_vector_type(8))) short frag8;   // 8 x bf16
typedef __attribute__((ext_vector_type(4))) short frag4;   // 4 x bf16
typedef __attribute__((ext_vector_type(4))) float f32x4;

#define MFMA16(A, Bf, C) __builtin_amdgcn_mfma_f32_16x16x32_bf16((A), (Bf), (C), 0, 0, 0)

__device__ __forceinline__ f32x4 mfma_16x16x16_bf16(frag4 a, frag4 b, f32x4 c) {
#if defined(__HIP_DEVICE_COMPILE__)
  return __builtin_amdgcn_mfma_f32_16x16x16bf16_1k(a, b, c, 0, 0, 0);
#else
  (void)a; (void)b;
  return c;
#endif
}

#define GLD16(g, l)                                                              \
  __builtin_amdgcn_global_load_lds((const __attribute__((address_space(1))) u32*)(g), \
                                   (__attribute__((address_space(3))) u32*)(l), 16, 0, 0)
#define EXP2(x) exp2f(x)

__device__ __forceinline__ u16 f2bf(float f) {          // RNE (epilogues/GEMM)
  union { float f; u32 u; } c; c.f = f;
  u32 u = c.u + 0x7fffu + ((c.u >> 16) & 1u);
  return (u16)(u >> 16);
}

#if defined(__HIP_DEVICE_COMPILE__)
__device__ __forceinline__ u32 cvtpk_bf16(float lo, float hi) {  // {hi:bf16(hi), lo:bf16(lo)} RNE
  u32 r;
  asm("v_cvt_pk_bf16_f32 %0, %1, %2" : "=v"(r) : "v"(lo), "v"(hi));
  return r;
}
#else
__device__ __forceinline__ u32 cvtpk_bf16(float lo, float hi) { (void)lo; (void)hi; return 0; }
#endif

__device__ __forceinline__ frag4 pack4_bf16(float a, float b, float c, float d) {
  union { u32 u[2]; frag4 f; } x;
  x.u[0] = cvtpk_bf16(a, b);
  x.u[1] = cvtpk_bf16(c, d);
  return x.f;
}

__device__ __forceinline__ void wait_lgkm0() {
  asm volatile("s_waitcnt lgkmcnt(0)" ::: "memory");
  __builtin_amdgcn_sched_barrier(0);
}
__device__ __forceinline__ void hbar() {
  __builtin_amdgcn_sched_barrier(0);
  __builtin_amdgcn_s_barrier();
  __builtin_amdgcn_sched_barrier(0);
}

// ---------------- fp32 -> bf16 convert, all buffers in one launch ----------------
__global__ void cvt_all(const float* __restrict__ X,  const float* __restrict__ Wq,
                        const float* __restrict__ Wk, const float* __restrict__ Wv,
                        const float* __restrict__ Wo,
                        u16* Xb, u16* Wqb, u16* Wkb, u16* Wvb, u16* Wob) {
  const int chunk = blockIdx.y;
  const float* src; u16* dst;
  if (chunk < 4)      { src = X + (size_t)chunk * 1048576; dst = Xb + (size_t)chunk * 1048576; }
  else if (chunk == 4){ src = Wq; dst = Wqb; }
  else if (chunk == 5){ src = Wk; dst = Wkb; }
  else if (chunk == 6){ src = Wv; dst = Wvb; }
  else                { src = Wo; dst = Wob; }
  int i = blockIdx.x * 256 + threadIdx.x;
  float4 v = ((const float4*)src)[i];
  u32 lo = (u32)f2bf(v.x) | ((u32)f2bf(v.y) << 16);
  u32 hi = (u32)f2bf(v.z) | ((u32)f2bf(v.w) << 16);
  ((uint2*)dst)[i] = make_uint2(lo, hi);
}

// ---------------- QKV as one 4096x3072x1024 GEMM, 8-phase schedule ----------------
// Wall = Wqb (Wq/Wk/Wv contiguous, 3072 rows x 1024 K each, K-major).
#define GQ_NT 16
__global__ __launch_bounds__(512, 2) void gemm_qkv8(const u16* __restrict__ Xb,
    const u16* __restrict__ Wall,
    const float* __restrict__ bq, const float* __restrict__ bk, const float* __restrict__ bv,
    u16* __restrict__ Qb, u16* __restrict__ Kb, u16* __restrict__ Vt) {
  __shared__ u16 As[2][16384];   // 256 rows x 64 cols, swizzled, 32 KB per buf
  __shared__ u16 Bs[2][12288];   // 192 rows x 64 cols, swizzled, 24 KB per buf

  const int tid = threadIdx.x, lane = tid & 63;
  const int wv = tid >> 6, l15 = lane & 15, quad = lane >> 4;
  const int wm = wv & 1, wn = wv >> 1;              // 2 x 4 wave grid

  // XCD-aware swizzle (bijective, 256 % 8 == 0): XCD x gets 2 contiguous M-panels
  const int bid = blockIdx.x;
  const int wgid = (bid & 7) * 32 + (bid >> 3);
  const int bm = (wgid >> 4) * 256;
  const int bn = (wgid & 15) * 192;

  // --- staging: A chunks lo={rows 0-63,128-191} hi={64-127,192-255}; B chunk j = col-stripes k*48+j*16 ---
  const u16* srcA[4]; int ldsA[4];
#pragma unroll
  for (int g = 0; g < 4; ++g) {
    int r = ((g & 1) << 7) + ((g >> 1) << 6) + (tid >> 3);
    int c8 = (tid & 7) ^ (r & 7);
    srcA[g] = Xb + (size_t)(bm + r) * DM + c8 * 8;
    ldsA[g] = r * 128 + (tid & 7) * 16;
  }
  const u16* srcB[3]; int ldsB[3];
#pragma unroll
  for (int j = 0; j < 3; ++j) {
    int sr = tid >> 3;
    int rb = (sr >> 4) * 48 + j * 16 + (sr & 15);
    int c8 = (tid & 7) ^ (rb & 7);
    srcB[j] = Wall + (size_t)(bn + rb) * DM + c8 * 8;
    ldsB[j] = rb * 128 + (tid & 7) * 16;
  }

  // --- ds_read offsets (same swizzle family as staging) ---
  int offA[8][2], offB[3][2];
#pragma unroll
  for (int i = 0; i < 8; ++i)
#pragma unroll
    for (int h = 0; h < 2; ++h) {
      int mA = wm * 128 + i * 16 + l15;
      offA[i][h] = mA * 128 + (((quad + h * 4) ^ (l15 & 7)) << 4);
    }
#pragma unroll
  for (int j = 0; j < 3; ++j)
#pragma unroll
    for (int h = 0; h < 2; ++h) {
      int mB = wn * 48 + j * 16 + l15;
      offB[j][h] = mB * 128 + (((quad + h * 4) ^ (l15 & 7)) << 4);
    }

  f32x4 acc[8][3] = {};
  frag8 aL[4][2], aH[4][2], b01[2][2], b2[2];

  // --- prologue: stage tiles 0 and 1, wait tile 0 (7 loads pending = tile 1) ---
#pragma unroll
  for (int g = 0; g < 2; ++g) GLD16(srcA[g], (char*)As[0] + ldsA[g]);
#pragma unroll
  for (int j = 0; j < 3; ++j) GLD16(srcB[j], (char*)Bs[0] + ldsB[j]);
#pragma unroll
  for (int g = 2; g < 4; ++g) GLD16(srcA[g], (char*)As[0] + ldsA[g]);
#pragma unroll
  for (int g = 0; g < 2; ++g) GLD16(srcA[g] + 64, (char*)As[1] + ldsA[g]);
#pragma unroll
  for (int j = 0; j < 3; ++j) GLD16(srcB[j] + 64, (char*)Bs[1] + ldsB[j]);
#pragma unroll
  for (int g = 2; g < 4; ++g) GLD16(srcA[g] + 64, (char*)As[1] + ldsA[g]);
  asm volatile("s_waitcnt vmcnt(7)" ::: "memory");
  hbar();

#pragma unroll 1
  for (int t = 0; t < GQ_NT; ++t) {
    const char* Ab = (const char*)As[t & 1];
    const char* Bb = (const char*)Bs[t & 1];
    const int tp = t + 2;
    const bool pf = (tp < GQ_NT);
    const int ko = tp * 64;

    // ---- ph0: quadrant (M-lo, j0..1). reads: aL(8) + b01(4). no issues. ----
#pragma unroll
    for (int i = 0; i < 4; ++i) {
      aL[i][0] = *(const frag8*)(Ab + offA[i][0]);
      aL[i][1] = *(const frag8*)(Ab + offA[i][1]);
    }
#pragma unroll
    for (int j = 0; j < 2; ++j) {
      b01[j][0] = *(const frag8*)(Bb + offB[j][0]);
      b01[j][1] = *(const frag8*)(Bb + offB[j][1]);
    }
    hbar();
    wait_lgkm0();
    __builtin_amdgcn_s_setprio(1);
#pragma unroll
    for (int h = 0; h < 2; ++h)
#pragma unroll
      for (int i = 0; i < 4; ++i)
#pragma unroll
        for (int j = 0; j < 2; ++j)
          acc[i][j] = MFMA16(aL[i][h], b01[j][h], acc[i][j]);
    __builtin_amdgcn_s_setprio(0);
    hbar();

    // ---- ph1: quadrant (M-lo, j2). reads: b2(2). issues: A-lo,B0,B1 of t+2. ----
    b2[0] = *(const frag8*)(Bb + offB[2][0]);
    b2[1] = *(const frag8*)(Bb + offB[2][1]);
    if (pf) {
      GLD16(srcA[0] + ko, (char*)As[tp & 1] + ldsA[0]);
      GLD16(srcA[1] + ko, (char*)As[tp & 1] + ldsA[1]);
      GLD16(srcB[0] + ko, (char*)Bs[tp & 1] + ldsB[0]);
      GLD16(srcB[1] + ko, (char*)Bs[tp & 1] + ldsB[1]);
    }
    hbar();
    wait_lgkm0();
    __builtin_amdgcn_s_setprio(1);
#pragma unroll
    for (int h = 0; h < 2; ++h)
#pragma unroll
      for (int i = 0; i < 4; ++i)
        acc[i][2] = MFMA16(aL[i][h], b2[h], acc[i][2]);
    __builtin_amdgcn_s_setprio(0);
    hbar();

    // ---- ph2: quadrant (M-hi, j0..1). reads: aH(8). issues: B2 of t+2. ----
#pragma unroll
    for (int i = 0; i < 4; ++i) {
      aH[i][0] = *(const frag8*)(Ab + offA[4 + i][0]);
      aH[i][1] = *(const frag8*)(Ab + offA[4 + i][1]);
    }
    if (pf) GLD16(srcB[2] + ko, (char*)Bs[tp & 1] + ldsB[2]);
    hbar();
    wait_lgkm0();
    __builtin_amdgcn_s_setprio(1);
#pragma unroll
    for (int h = 0; h < 2; ++h)
#pragma unroll
      for (int i = 0; i < 4; ++i)
#pragma unroll
        for (int j = 0; j < 2; ++j)
          acc[4 + i][j] = MFMA16(aH[i][h], b01[j][h], acc[4 + i][j]);
    __builtin_amdgcn_s_setprio(0);
    hbar();

    // ---- ph3: quadrant (M-hi, j2). no reads. issues: A-hi of t+2. boundary vmcnt. ----
    if (pf) {
      GLD16(srcA[2] + ko, (char*)As[tp & 1] + ldsA[2]);
      GLD16(srcA[3] + ko, (char*)As[tp & 1] + ldsA[3]);
    }
    hbar();
    __builtin_amdgcn_s_setprio(1);
#pragma unroll
    for (int h = 0; h < 2; ++h)
#pragma unroll
      for (int i = 0; i < 4; ++i)
        acc[4 + i][2] = MFMA16(aH[i][h], b2[h], acc[4 + i][2]);
    __builtin_amdgcn_s_setprio(0);
    if (t < GQ_NT - 2) asm volatile("s_waitcnt vmcnt(7)" ::: "memory");
    else               asm volatile("s_waitcnt vmcnt(0)" ::: "memory");
    hbar();
  }

  // ---- epilogue: per-frag Q/K/V resolve (wave-uniform per j) ----
#pragma unroll
  for (int j = 0; j < 3; ++j) {
    int col = bn + wn * 48 + j * 16 + l15;      // 0..3071
    int which = col >> 10, lc = col & 1023;
    const float* bias = (which == 0) ? bq : (which == 1) ? bk : bv;
    float bb = bias[lc];
    if (which < 2) {
      u16* O = (which == 0) ? Qb : Kb;
      const float scl = (which == 0) ? SCL2 : 1.0f;
#pragma unroll
      for (int i = 0; i < 8; ++i) {
        int row0 = bm + wm * 128 + i * 16 + quad * 4;
#pragma unroll
        for (int r = 0; r < 4; ++r)
          O[(size_t)(row0 + r) * DM + lc] = f2bf((acc[i][j][r] + bb) * scl);
      }
    } else {
#pragma unroll
      for (int i = 0; i < 8; ++i) {
        int row0 = bm + wm * 128 + i * 16 + quad * 4;
        u32 lo = (u32)f2bf(acc[i][j][0] + bb) | ((u32)f2bf(acc[i][j][1] + bb) << 16);
        u32 hi = (u32)f2bf(acc[i][j][2] + bb) | ((u32)f2bf(acc[i][j][3] + bb) << 16);
        *(uint2*)&Vt[(size_t)lc * BS_ + row0] = make_uint2(lo, hi);
      }
    }
  }
}

// ---------------- Wo GEMM: 64x128 tile, 512 blocks (2/CU), 256 threads ----------------
__global__ __launch_bounds__(256, 3) void gemm_wo(const u16* __restrict__ Cx,
    const u16* __restrict__ Wob, const float* __restrict__ bo, float* __restrict__ out) {
  __shared__ u16 As[4096], Bs[8192];   // A 64x64, B 128x64 (swizzled)
  const int tid = threadIdx.x;
  const int wv = tid >> 6, lane = tid & 63, l15 = lane & 15, quad = lane >> 4;
  const int bm = blockIdx.y * 64, bn = blockIdx.x * 128;

  const u16* gA[2]; const u16* gB[4];
  int ldsA[2], ldsB[4];
#pragma unroll
  for (int c = 0; c < 2; ++c) {
    int slot = c * 256 + wv * 64 + lane;
    int r = slot >> 3, cb = (slot & 7) ^ (r & 7);
    gA[c] = Cx + (size_t)(bm + r) * DM + cb * 8;
    ldsA[c] = (c * 256 + wv * 64) * 16;
  }
#pragma unroll
  for (int c = 0; c < 4; ++c) {
    int slot = c * 256 + wv * 64 + lane;
    int r = slot >> 3, cb = (slot & 7) ^ (r & 7);
    gB[c] = Wob + (size_t)(bn + r) * DM + cb * 8;
    ldsB[c] = (c * 256 + wv * 64) * 16;
  }

  int offA[2], offB[8][2];
#pragma unroll
  for (int h = 0; h < 2; ++h) {
    int rowA = wv * 16 + l15;
    offA[h] = ((rowA << 3) + ((quad + h * 4) ^ (l15 & 7))) << 4;
#pragma unroll
    for (int j = 0; j < 8; ++j) {
      int rowB = j * 16 + l15;
      offB[j][h] = ((rowB << 3) + ((quad + h * 4) ^ (l15 & 7))) << 4;
    }
  }

  f32x4 acc[8] = {};
  for (int k0 = 0; k0 < DM; k0 += 64) {
#pragma unroll
    for (int c = 0; c < 2; ++c) GLD16(gA[c] + k0, (char*)As + ldsA[c]);
#pragma unroll
    for (int c = 0; c < 4; ++c) GLD16(gB[c] + k0, (char*)Bs + ldsB[c]);
    __syncthreads();
    frag8 af0 = *(const frag8*)((const char*)As + offA[0]);
    frag8 af1 = *(const frag8*)((const char*)As + offA[1]);
#pragma unroll
    for (int j = 0; j < 8; ++j) {
      frag8 bf0 = *(const frag8*)((const char*)Bs + offB[j][0]);
      frag8 bf1 = *(const frag8*)((const char*)Bs + offB[j][1]);
      acc[j] = MFMA16(af0, bf0, acc[j]);
      acc[j] = MFMA16(af1, bf1, acc[j]);
    }
    __syncthreads();
  }

#pragma unroll
  for (int j = 0; j < 8; ++j) {
    int col = bn + j * 16 + l15;
    float bb = bo[col];
    int row0 = bm + wv * 16 + quad * 4;
#pragma unroll
    for (int r = 0; r < 4; ++r)
      out[(size_t)(row0 + r) * DM + col] = acc[j][r] + bb;
  }
}

// ---------------- Flash attention: 128-q blocks, LDS-staged, chained MFMA ----------------
// Units per bh: 8 heavy-split (strips 0..1 of 128 q x 4 segs of 8 tiles) +
// 14 light (128-q strips, q0 = 256+128i, tile-skip loop). Grid 22*32 = 704
// blocks — fully co-resident at 3/CU. Each wave: two 16-q groups (q, q+64)
// share the staged K/V tile. mmode per tile: 0 = all active, 2 = window|NG-
// cols (kt==3 only), 1 = window|row-global (group-skippable).
__global__ __launch_bounds__(256, 3) void attn_kernel(const u16* __restrict__ Q,
                                                      const u16* __restrict__ K,
                                                      const u16* __restrict__ Vt,
                                                      u16* __restrict__ Ctx,
                                                      float* __restrict__ Op,
                                                      float* __restrict__ Lp) {
  __shared__ u16 Ks[2][4096];     // [buf][64 keys x 64 d] swizzled
  __shared__ u16 Vs[2][4096];     // [buf][64 d x 64 keys] swizzled

  const int tid = threadIdx.x, w = tid >> 6, lane = tid & 63, l15 = lane & 15, quad = lane >> 4;
  const int blk = blockIdx.x;
  const int bh = blk & 31, unit = blk >> 5;
  const int b = bh >> 4, h = bh & 15;
  const bool heavy = unit < 8;
  const int strip = heavy ? (unit >> 2) : 0;
  const int q0 = heavy ? strip * 128 : 256 + (unit - 8) * 128;
  const int qw = q0 + w * 16;      // group g covers qw + g*64 .. +15

  // Q B-frags per group (n = q = l15, k = d = quad*8+j); Q carries SCL2
  frag8 bq[2][2];
#pragma unroll
  for (int g = 0; g < 2; ++g) {
    const u16* qrow = Q + (size_t)(b * S_ + qw + g * 64 + l15) * DM + h * 64;
    bq[g][0] = *(const frag8*)(qrow + quad * 8);
    bq[g][1] = *(const frag8*)(qrow + quad * 8 + 32);
  }

  // staging pointers; swizzle f(r) = (r&7) ^ (((r>>3)&1)<<2)
  const u16* gK[2]; const u16* gV[2]; int ldso[2];
#pragma unroll
  for (int c = 0; c < 2; ++c) {
    int sl = (w * 2 + c) * 64 + lane;
    int r = sl >> 3;
    int fr = (r & 7) ^ (((r >> 3) & 1) << 2);
    int cb = (sl & 7) ^ fr;
    gK[c] = K  + (size_t)(b * S_ + r) * DM + h * 64 + cb * 8;        // + kt*64*DM
    gV[c] = Vt + (size_t)(h * 64 + r) * BS_ + (size_t)b * S_ + cb * 8;  // + kt*64
    ldso[c] = (w * 2 + c) * 1024;
  }

  const int fl = (l15 & 7) ^ (((l15 >> 3) & 1) << 2);   // f(row) for row%16 = l15
  int offKb[2];
#pragma unroll
  for (int hh = 0; hh < 2; ++hh)
    offKb[hh] = ((l15 << 3) + ((quad + hh * 4) ^ fl)) << 4;
  int offVb[4];
#pragma unroll
  for (int kg = 0; kg < 4; ++kg)
    offVb[kg] = ((((l15 << 3) + ((((kg << 1) | (quad >> 1))) ^ fl)) << 4)
                 | ((quad & 1) << 3));

  // per-lane window test constants: act iff (u32)(kc - mlo) <= mspan,
  // with global rows (q < NG) forced always-active via span = ALL.
  int mlo[2]; u32 mspan[2];
#pragma unroll
  for (int g = 0; g < 2; ++g) {
    int qi = qw + g * 64 + l15;
    bool qg = qi < NG;
    mlo[g]   = qg ? (int)0x80000000 : (qi - 64);
    mspan[g] = qg ? 0xFFFFFFFFu : 128u;
  }
  const frag4 ones = {(short)0x3F80, (short)0x3F80, (short)0x3F80, (short)0x3F80};

  f32x4 o[2][4] = {};     // O^T per group: row d = nt*16+quad*4+r, col q = l15
  f32x4 o_l[2] = {};      // lsum per group via ones-MFMA

  auto stage = [&](int t, int buf) {
#pragma unroll
    for (int c = 0; c < 2; ++c) {
      GLD16(gK[c] + (size_t)t * 64 * DM, (char*)Ks[buf] + ldso[c]);
      GLD16(gV[c] + t * 64,              (char*)Vs[buf] + ldso[c]);
    }
  };

  auto step = [&](int kt, int p, int mmode) {
    int gok0 = 1, gok1 = 1;
    if (mmode == 1) {       // window | row-global only: groups can be skipped
      const int k0s = kt * 64;
      const int ql1 = qw + 64;
      gok0 = (qw  < NG) || ((k0s + 63 >= qw  - 64) && (k0s <= qw  + 79));
      gok1 = (ql1 < NG) || ((k0s + 63 >= ql1 - 64) && (k0s <= ql1 + 79));
      if (!(gok0 | gok1)) return;
    }
    const char* kb_ = (const char*)Ks[p];
    const char* vb_ = (const char*)Vs[p];
    // K A-frags loaded once, used by both q-groups
    frag8 ak[4][2];
#pragma unroll
    for (int kg = 0; kg < 4; ++kg) {
      ak[kg][0] = *(const frag8*)(kb_ + offKb[0] + kg * 2048);
      ak[kg][1] = *(const frag8*)(kb_ + offKb[1] + kg * 2048);
    }
    const int k0 = kt * 64;
    const int gok[2] = {gok0, gok1};
    frag4 pk[2][4];
#pragma unroll
    for (int g = 0; g < 2; ++g) {
      if (!gok[g]) continue;
      f32x4 st[4] = {};
#pragma unroll
      for (int kg = 0; kg < 4; ++kg) {
        st[kg] = MFMA16(ak[kg][0], bq[g][0], st[kg]);
        st[kg] = MFMA16(ak[kg][1], bq[g][1], st[kg]);
      }
      if (mmode) {
#pragma unroll
        for (int kg = 0; kg < 4; ++kg) {
          float pr[4];
#pragma unroll
          for (int r = 0; r < 4; ++r) {
            int kc = k0 + kg * 16 + quad * 4 + r;
            bool act = ((u32)(kc - mlo[g]) <= mspan[g]);
            if (mmode == 2) act = act || (kc < NG);
            float e = EXP2(st[kg][r]);      // scores finite; exp issues early
            pr[r] = act ? e : 0.0f;
          }
          pk[g][kg] = pack4_bf16(pr[0], pr[1], pr[2], pr[3]);
        }
      } else {
#pragma unroll
        for (int kg = 0; kg < 4; ++kg)
          pk[g][kg] = pack4_bf16(EXP2(st[kg][0]), EXP2(st[kg][1]),
                                 EXP2(st[kg][2]), EXP2(st[kg][3]));
      }
    }
    // PV: V^T frags read once; static group indices in each branch (no
    // runtime-indexed register arrays)
    if (gok0 & gok1) {
#pragma unroll
      for (int kg = 0; kg < 4; ++kg) {
        o_l[0] = mfma_16x16x16_bf16(ones, pk[0][kg], o_l[0]);
        o_l[1] = mfma_16x16x16_bf16(ones, pk[1][kg], o_l[1]);
#pragma unroll
        for (int nt = 0; nt < 4; ++nt) {
          frag4 av = *(const frag4*)(vb_ + offVb[kg] + nt * 2048);
          o[0][nt] = mfma_16x16x16_bf16(av, pk[0][kg], o[0][nt]);
          o[1][nt] = mfma_16x16x16_bf16(av, pk[1][kg], o[1][nt]);
        }
      }
    } else if (gok0) {
#pragma unroll
      for (int kg = 0; kg < 4; ++kg) {
        o_l[0] = mfma_16x16x16_bf16(ones, pk[0][kg], o_l[0]);
#pragma unroll
        for (int nt = 0; nt < 4; ++nt) {
          frag4 av = *(const frag4*)(vb_ + offVb[kg] + nt * 2048);
          o[0][nt] = mfma_16x16x16_bf16(av, pk[0][kg], o[0][nt]);
        }
      }
    } else {
#pragma unroll
      for (int kg = 0; kg < 4; ++kg) {
        o_l[1] = mfma_16x16x16_bf16(ones, pk[1][kg], o_l[1]);
#pragma unroll
        for (int nt = 0; nt < 4; ++nt) {
          frag4 av = *(const frag4*)(vb_ + offVb[kg] + nt * 2048);
          o[1][nt] = mfma_16x16x16_bf16(av, pk[1][kg], o[1][nt]);
        }
      }
    }
  };

  if (heavy) {
    const int seg = unit & 3;
    const int kt0 = seg * 8;
    const bool dm = (strip == 1);         // q 128..255 straddles NG cutoff
    int p = 0;
    stage(kt0, 0);
#pragma unroll 1
    for (int tt = 0; tt < 8; ++tt) {
      __syncthreads();
      if (tt < 7) stage(kt0 + tt + 1, p ^ 1);
      const int kt = kt0 + tt;
      const int mm = dm ? ((kt == 3) ? 2 : ((kt > 2) ? 1 : 0)) : 0;
      step(kt, p, mm);
      p ^= 1;
    }
    // partials: Op[(bh*2+strip)*4+seg][q 0..127][d 0..63], Lp[...][q 0..127]
    float* op = Op + ((size_t)((bh * 2 + strip) * 4 + seg)) * 8192;
    float* lp = Lp + ((size_t)((bh * 2 + strip) * 4 + seg)) * 128;
#pragma unroll
    for (int g = 0; g < 2; ++g) {
      int rl = g * 64 + w * 16 + l15;
      if (quad == 0) lp[rl] = o_l[g][0];
#pragma unroll
      for (int nt = 0; nt < 4; ++nt)
        *(float4*)&op[rl * 64 + nt * 16 + quad * 4] =
            make_float4(o[g][nt][0], o[g][nt][1], o[g][nt][2], o[g][nt][3]);
    }
    return;
  }

  // light path: q0 >= 256, tile-skip loop (global cols 0..3 + window band)
  auto activef = [&](int t) {
    int k0 = t * 64;
    return (k0 < NG) || (k0 + 63 >= q0 - 64 && k0 <= q0 + 127 + 64);
  };
  auto nextt = [&](int cur) { int n = cur + 1; while (n < 32 && !activef(n)) ++n; return n; };

  int kt = 0, p = 0;                      // tile 0 always active (global cols)
  stage(0, 0);
  for (;;) {
    int ktn = nextt(kt);
    bool more = ktn < 32;
    __syncthreads();
    if (more) stage(ktn, p ^ 1);
    const int mm = (kt == 3) ? 2 : ((kt > 2) ? 1 : 0);
    step(kt, p, mm);
    if (!more) break;
    kt = ktn; p ^= 1;
  }

#pragma unroll
  for (int g = 0; g < 2; ++g) {
    float inv = 1.0f / o_l[g][0];
    u16* crow = Ctx + (size_t)((size_t)b * S_ + qw + g * 64 + l15) * DM + h * 64;
#pragma unroll
    for (int nt = 0; nt < 4; ++nt) {
      u32 lo = (u32)f2bf(o[g][nt][0] * inv) | ((u32)f2bf(o[g][nt][1] * inv) << 16);
      u32 hi = (u32)f2bf(o[g][nt][2] * inv) | ((u32)f2bf(o[g][nt][3] * inv) << 16);
      *(uint2*)&crow[nt * 16 + quad * 4] = make_uint2(lo, hi);
    }
  }
}

// ---------------- combine split-K partials -> Ctx rows 0..255 ----------------
// 128 blocks (4 strips of 64 q x 32 bh), 256 thr: row = t>>2, 16 d-cols each.
__global__ __launch_bounds__(256) void combine_kernel(const float* __restrict__ Op,
                                                      const float* __restrict__ Lp,
                                                      u16* __restrict__ Ctx) {
  const int blk = blockIdx.x;
  const int bh = blk & 31, s64 = blk >> 5;      // 64-row strip 0..3
  const int b = bh >> 4, h = bh & 15;
  const int t = threadIdx.x;
  const int row = t >> 2, colg = (t & 3) * 16;
  const int gq = s64 * 64 + row;                 // 0..255
  const int strip = gq >> 7, rIn = gq & 127;     // 128-row partial index

  const float* opb = Op + ((size_t)(bh * 2 + strip) * 4) * 8192;
  const float* lpb = Lp + ((size_t)(bh * 2 + strip) * 4) * 128;

  float l = lpb[rIn] + lpb[128 + rIn] + lpb[256 + rIn] + lpb[384 + rIn];
  float acc[16];
#pragma unroll
  for (int e = 0; e < 16; ++e) acc[e] = opb[rIn * 64 + colg + e];
#pragma unroll
  for (int seg = 1; seg < 4; ++seg)
#pragma unroll
    for (int e = 0; e < 16; ++e) acc[e] += opb[seg * 8192 + rIn * 64 + colg + e];

  float inv = 1.0f / l;
  u32 pk[8];
#pragma unroll
  for (int p = 0; p < 8; ++p)
    pk[p] = (u32)f2bf(acc[2 * p] * inv) | ((u32)f2bf(acc[2 * p + 1] * inv) << 16);
  u16* dst = Ctx + (size_t)((size_t)b * S_ + gq) * DM + h * 64 + colg;
  *(uint4*)dst       = make_uint4(pk[0], pk[1], pk[2], pk[3]);
  *(uint4*)(dst + 8) = make_uint4(pk[4], pk[5], pk[6], pk[7]);
}

// ---------------- launch ----------------
extern "C" void kernel_launch(void* const* d_in, const int* in_sizes, int n_in,
                              void* d_out, int out_size, void* d_ws, size_t ws_size,
                              hipStream_t stream) {
  const float* X  = (const float*)d_in[0];
  const float* Wq = (const float*)d_in[1];
  const float* bq = (const float*)d_in[2];
  const float* Wk = (const float*)d_in[3];
  const float* bk = (const float*)d_in[4];
  const float* Wv = (const float*)d_in[5];
  const float* bv = (const float*)d_in[6];
  const float* Wo = (const float*)d_in[7];
  const float* bo = (const float*)d_in[8];
  float* out = (float*)d_out;

  u16* ws = (u16*)d_ws;
  const size_t NX = (size_t)BS_ * DM;
  const size_t NW = (size_t)DM * DM;
  u16* Xb  = ws;
  u16* Wqb = Xb + NX;
  u16* Wkb = Wqb + NW;
  u16* Wvb = Wkb + NW;
  u16* Wob = Wvb + NW;
  u16* Qb  = Wob + NW;
  u16* Kb  = Qb + NX;
  u16* Vt  = Kb + NX;
  u16* Cx  = Vt + NX;
  float* Op = (float*)(Cx + NX);               // 32*2*4*8192 = 2.1M floats (8 MB)
  float* Lp = Op + (size_t)32 * 2 * 4 * 8192;  // 32k floats

  cvt_all<<<dim3(1024, 8), 256, 0, stream>>>(X, Wq, Wk, Wv, Wo, Xb, Wqb, Wkb, Wvb, Wob);
  gemm_qkv8<<<256, 512, 0, stream>>>(Xb, Wqb, bq, bk, bv, Qb, Kb, Vt);
  attn_kernel<<<22 * 32, 256, 0, stream>>>(Qb, Kb, Vt, Cx, Op, Lp);
  combine_kernel<<<128, 256, 0, stream>>>(Op, Lp, Cx);
  gemm_wo<<<dim3(8, 64), 256, 0, stream>>>(Cx, Wob, bo, out);
}

// Round 3
// 170.700 us; speedup vs baseline: 1.0359x; 1.0359x over previous
//
#include <hip/hip_runtime.h>

// LongformerAttention MI355X — Round 13.
// Revert gemm_qkv to R11's proven 128x128 m97-structure (R12's 8-phase
// rewrite was latency-bound: 43.4 us, MfmaUtil 21%). gemm_wo upgraded from
// 64x128 tile (~500 TF) to the same 128x128 mainloop as gemm_qkv
// (grid 8x32, 3/CU), f32 epilogue with bias. attn/cvt/combine unchanged.

#define B_   2
#define S_   2048
#define DM   1024
#define H_   16
#define NG   204                     // max(1, int(S*0.1))
#define BS_  4096                    // B_*S_
#define SCL2 0.1803368801111204f     // (1/sqrt(64)) * log2(e)  — folded into Q
#define NEGF -3.0e38f

typedef unsigned short u16;
typedef unsigned int   u32;
typedef __attribute__((ext_vector_type(8))) short frag8;   // 8 x bf16
typedef __attribute__((ext_vector_type(4))) short frag4;   // 4 x bf16
typedef __attribute__((ext_vector_type(4))) float f32x4;

#define MFMA16(A, Bf, C) __builtin_amdgcn_mfma_f32_16x16x32_bf16((A), (Bf), (C), 0, 0, 0)

__device__ __forceinline__ f32x4 mfma_16x16x16_bf16(frag4 a, frag4 b, f32x4 c) {
#if defined(__HIP_DEVICE_COMPILE__)
  return __builtin_amdgcn_mfma_f32_16x16x16bf16_1k(a, b, c, 0, 0, 0);
#else
  (void)a; (void)b;
  return c;
#endif
}

#define GLD16(g, l)                                                              \
  __builtin_amdgcn_global_load_lds((const __attribute__((address_space(1))) u32*)(g), \
                                   (__attribute__((address_space(3))) u32*)(l), 16, 0, 0)
#define EXP2(x) exp2f(x)

__device__ __forceinline__ u16 f2bf(float f) {          // RNE (epilogues/GEMM)
  union { float f; u32 u; } c; c.f = f;
  u32 u = c.u + 0x7fffu + ((c.u >> 16) & 1u);
  return (u16)(u >> 16);
}

#if defined(__HIP_DEVICE_COMPILE__)
__device__ __forceinline__ u32 cvtpk_bf16(float lo, float hi) {  // {hi:bf16(hi), lo:bf16(lo)} RNE
  u32 r;
  asm("v_cvt_pk_bf16_f32 %0, %1, %2" : "=v"(r) : "v"(lo), "v"(hi));
  return r;
}
#else
__device__ __forceinline__ u32 cvtpk_bf16(float lo, float hi) { (void)lo; (void)hi; return 0; }
#endif

__device__ __forceinline__ frag4 pack4_bf16(float a, float b, float c, float d) {
  union { u32 u[2]; frag4 f; } x;
  x.u[0] = cvtpk_bf16(a, b);
  x.u[1] = cvtpk_bf16(c, d);
  return x.f;
}

// ---------------- fp32 -> bf16 convert, all buffers in one launch ----------------
__global__ void cvt_all(const float* __restrict__ X,  const float* __restrict__ Wq,
                        const float* __restrict__ Wk, const float* __restrict__ Wv,
                        const float* __restrict__ Wo,
                        u16* Xb, u16* Wqb, u16* Wkb, u16* Wvb, u16* Wob) {
  const int chunk = blockIdx.y;
  const float* src; u16* dst;
  if (chunk < 4)      { src = X + (size_t)chunk * 1048576; dst = Xb + (size_t)chunk * 1048576; }
  else if (chunk == 4){ src = Wq; dst = Wqb; }
  else if (chunk == 5){ src = Wk; dst = Wkb; }
  else if (chunk == 6){ src = Wv; dst = Wvb; }
  else                { src = Wo; dst = Wob; }
  int i = blockIdx.x * 256 + threadIdx.x;
  float4 v = ((const float4*)src)[i];
  u32 lo = (u32)f2bf(v.x) | ((u32)f2bf(v.y) << 16);
  u32 hi = (u32)f2bf(v.z) | ((u32)f2bf(v.w) << 16);
  ((uint2*)dst)[i] = make_uint2(lo, hi);
}

// ---------------- m97-style GEMM mainloop, 256 threads, 128x128 tile ----------------
__device__ __forceinline__ void gemm_mainloop(const u16* __restrict__ A, const u16* __restrict__ Bm,
                                              int bm, int bn, u16* As, u16* Bs,
                                              f32x4 acc[4][4]) {
  const int tid = threadIdx.x;
  const int wv = tid >> 6, lane = tid & 63, l15 = lane & 15, quad = lane >> 4;
  const int wm = wv & 1, wn = wv >> 1;

  const u16* gA[4]; const u16* gB[4];
#pragma unroll
  for (int c = 0; c < 4; ++c) {
    int idx = (wv * 4 + c) * 64 + lane;
    int r = idx >> 3;
    int cb = (idx & 7) ^ (r & 7);
    gA[c] = A  + (size_t)(bm + r) * DM + cb * 8;
    gB[c] = Bm + (size_t)(bn + r) * DM + cb * 8;
  }

  int offA[4][2], offB[4][2];
#pragma unroll
  for (int i = 0; i < 4; ++i)
#pragma unroll
    for (int h = 0; h < 2; ++h) {
      int mA = wm * 64 + i * 16 + l15;
      int mB = wn * 64 + i * 16 + l15;
      int cb = (quad + h * 4) ^ (l15 & 7);
      offA[i][h] = ((mA << 3) + cb) << 4;
      offB[i][h] = ((mB << 3) + cb) << 4;
    }

  for (int k0 = 0; k0 < DM; k0 += 64) {
#pragma unroll
    for (int c = 0; c < 4; ++c) {
      GLD16(gA[c] + k0, (char*)As + (wv * 4 + c) * 1024);
      GLD16(gB[c] + k0, (char*)Bs + (wv * 4 + c) * 1024);
    }
    __syncthreads();
    frag8 af[4][2], bf[4][2];
#pragma unroll
    for (int i = 0; i < 4; ++i) {
      af[i][0] = *(const frag8*)((const char*)As + offA[i][0]);
      af[i][1] = *(const frag8*)((const char*)As + offA[i][1]);
      bf[i][0] = *(const frag8*)((const char*)Bs + offB[i][0]);
      bf[i][1] = *(const frag8*)((const char*)Bs + offB[i][1]);
    }
#pragma unroll
    for (int h = 0; h < 2; ++h)
#pragma unroll
      for (int i = 0; i < 4; ++i)
#pragma unroll
        for (int j = 0; j < 4; ++j)
          acc[i][j] = MFMA16(af[i][h], bf[j][h], acc[i][j]);
    __syncthreads();
  }
}

__global__ __launch_bounds__(256, 3) void gemm_qkv(const u16* __restrict__ Xb,
    const u16* __restrict__ Wqb, const u16* __restrict__ Wkb, const u16* __restrict__ Wvb,
    const float* __restrict__ bq, const float* __restrict__ bk, const float* __restrict__ bv,
    u16* __restrict__ Qb, u16* __restrict__ Kb, u16* __restrict__ Vt) {
  __shared__ u16 As[8192], Bs[8192];
  const int bm = blockIdx.y * 128;
  const int which = blockIdx.x >> 3;
  const int bnl = (blockIdx.x & 7) * 128;
  const u16* W = (which == 0) ? Wqb : (which == 1) ? Wkb : Wvb;
  const float* bias = (which == 0) ? bq : (which == 1) ? bk : bv;

  f32x4 acc[4][4] = {};
  gemm_mainloop(Xb, W, bm, bnl, As, Bs, acc);

  const int tid = threadIdx.x, wv = tid >> 6, lane = tid & 63, l15 = lane & 15, quad = lane >> 4;
  const int wm = wv & 1, wn = wv >> 1;
  if (which < 2) {
    u16* O = (which == 0) ? Qb : Kb;
    const float scl = (which == 0) ? SCL2 : 1.0f;   // fold softmax scale into Q
#pragma unroll
    for (int j = 0; j < 4; ++j) {
      int col = bnl + wn * 64 + j * 16 + l15;
      float bb = bias[col];
#pragma unroll
      for (int i = 0; i < 4; ++i) {
        int row0 = bm + wm * 64 + i * 16 + quad * 4;
#pragma unroll
        for (int r = 0; r < 4; ++r)
          O[(size_t)(row0 + r) * DM + col] = f2bf((acc[i][j][r] + bb) * scl);
      }
    }
  } else {
#pragma unroll
    for (int j = 0; j < 4; ++j) {
      int col = bnl + wn * 64 + j * 16 + l15;
      float bb = bias[col];
#pragma unroll
      for (int i = 0; i < 4; ++i) {
        int row0 = bm + wm * 64 + i * 16 + quad * 4;
        u32 lo = (u32)f2bf(acc[i][j][0] + bb) | ((u32)f2bf(acc[i][j][1] + bb) << 16);
        u32 hi = (u32)f2bf(acc[i][j][2] + bb) | ((u32)f2bf(acc[i][j][3] + bb) << 16);
        *(uint2*)&Vt[(size_t)col * BS_ + row0] = make_uint2(lo, hi);
      }
    }
  }
}

// ---------------- Wo GEMM: 128x128 m97 tile, grid 8x32 = 256 blocks ----------------
__global__ __launch_bounds__(256, 3) void gemm_wo(const u16* __restrict__ Cx,
    const u16* __restrict__ Wob, const float* __restrict__ bo, float* __restrict__ out) {
  __shared__ u16 As[8192], Bs[8192];
  const int bm = blockIdx.y * 128, bn = blockIdx.x * 128;

  f32x4 acc[4][4] = {};
  gemm_mainloop(Cx, Wob, bm, bn, As, Bs, acc);

  const int tid = threadIdx.x, wv = tid >> 6, lane = tid & 63, l15 = lane & 15, quad = lane >> 4;
  const int wm = wv & 1, wn = wv >> 1;
#pragma unroll
  for (int j = 0; j < 4; ++j) {
    int col = bn + wn * 64 + j * 16 + l15;
    float bb = bo[col];
#pragma unroll
    for (int i = 0; i < 4; ++i) {
      int row0 = bm + wm * 64 + i * 16 + quad * 4;
#pragma unroll
      for (int r = 0; r < 4; ++r)
        out[(size_t)(row0 + r) * DM + col] = acc[i][j][r] + bb;
    }
  }
}

// ---------------- Flash attention: 128-q blocks, LDS-staged, chained MFMA ----------------
// Units per bh: 8 heavy-split (strips 0..1 of 128 q x 4 segs of 8 tiles) +
// 14 light (128-q strips, q0 = 256+128i, tile-skip loop). Grid 22*32 = 704
// blocks — fully co-resident at 3/CU. Each wave: two 16-q groups (q, q+64)
// share the staged K/V tile. mmode per tile: 0 = all active, 2 = window|NG-
// cols (kt==3 only), 1 = window|row-global (group-skippable).
__global__ __launch_bounds__(256, 3) void attn_kernel(const u16* __restrict__ Q,
                                                      const u16* __restrict__ K,
                                                      const u16* __restrict__ Vt,
                                                      u16* __restrict__ Ctx,
                                                      float* __restrict__ Op,
                                                      float* __restrict__ Lp) {
  __shared__ u16 Ks[2][4096];     // [buf][64 keys x 64 d] swizzled
  __shared__ u16 Vs[2][4096];     // [buf][64 d x 64 keys] swizzled

  const int tid = threadIdx.x, w = tid >> 6, lane = tid & 63, l15 = lane & 15, quad = lane >> 4;
  const int blk = blockIdx.x;
  const int bh = blk & 31, unit = blk >> 5;
  const int b = bh >> 4, h = bh & 15;
  const bool heavy = unit < 8;
  const int strip = heavy ? (unit >> 2) : 0;
  const int q0 = heavy ? strip * 128 : 256 + (unit - 8) * 128;
  const int qw = q0 + w * 16;      // group g covers qw + g*64 .. +15

  // Q B-frags per group (n = q = l15, k = d = quad*8+j); Q carries SCL2
  frag8 bq[2][2];
#pragma unroll
  for (int g = 0; g < 2; ++g) {
    const u16* qrow = Q + (size_t)(b * S_ + qw + g * 64 + l15) * DM + h * 64;
    bq[g][0] = *(const frag8*)(qrow + quad * 8);
    bq[g][1] = *(const frag8*)(qrow + quad * 8 + 32);
  }

  // staging pointers; swizzle f(r) = (r&7) ^ (((r>>3)&1)<<2)
  const u16* gK[2]; const u16* gV[2]; int ldso[2];
#pragma unroll
  for (int c = 0; c < 2; ++c) {
    int sl = (w * 2 + c) * 64 + lane;
    int r = sl >> 3;
    int fr = (r & 7) ^ (((r >> 3) & 1) << 2);
    int cb = (sl & 7) ^ fr;
    gK[c] = K  + (size_t)(b * S_ + r) * DM + h * 64 + cb * 8;        // + kt*64*DM
    gV[c] = Vt + (size_t)(h * 64 + r) * BS_ + (size_t)b * S_ + cb * 8;  // + kt*64
    ldso[c] = (w * 2 + c) * 1024;
  }

  const int fl = (l15 & 7) ^ (((l15 >> 3) & 1) << 2);   // f(row) for row%16 = l15
  int offKb[2];
#pragma unroll
  for (int hh = 0; hh < 2; ++hh)
    offKb[hh] = ((l15 << 3) + ((quad + hh * 4) ^ fl)) << 4;
  int offVb[4];
#pragma unroll
  for (int kg = 0; kg < 4; ++kg)
    offVb[kg] = ((((l15 << 3) + ((((kg << 1) | (quad >> 1))) ^ fl)) << 4)
                 | ((quad & 1) << 3));

  // per-lane window test constants: act iff (u32)(kc - mlo) <= mspan,
  // with global rows (q < NG) forced always-active via span = ALL.
  int mlo[2]; u32 mspan[2];
#pragma unroll
  for (int g = 0; g < 2; ++g) {
    int qi = qw + g * 64 + l15;
    bool qg = qi < NG;
    mlo[g]   = qg ? (int)0x80000000 : (qi - 64);
    mspan[g] = qg ? 0xFFFFFFFFu : 128u;
  }
  const frag4 ones = {(short)0x3F80, (short)0x3F80, (short)0x3F80, (short)0x3F80};

  f32x4 o[2][4] = {};     // O^T per group: row d = nt*16+quad*4+r, col q = l15
  f32x4 o_l[2] = {};      // lsum per group via ones-MFMA

  auto stage = [&](int t, int buf) {
#pragma unroll
    for (int c = 0; c < 2; ++c) {
      GLD16(gK[c] + (size_t)t * 64 * DM, (char*)Ks[buf] + ldso[c]);
      GLD16(gV[c] + t * 64,              (char*)Vs[buf] + ldso[c]);
    }
  };

  auto step = [&](int kt, int p, int mmode) {
    int gok0 = 1, gok1 = 1;
    if (mmode == 1) {       // window | row-global only: groups can be skipped
      const int k0s = kt * 64;
      const int ql1 = qw + 64;
      gok0 = (qw  < NG) || ((k0s + 63 >= qw  - 64) && (k0s <= qw  + 79));
      gok1 = (ql1 < NG) || ((k0s + 63 >= ql1 - 64) && (k0s <= ql1 + 79));
      if (!(gok0 | gok1)) return;
    }
    const char* kb_ = (const char*)Ks[p];
    const char* vb_ = (const char*)Vs[p];
    // K A-frags loaded once, used by both q-groups
    frag8 ak[4][2];
#pragma unroll
    for (int kg = 0; kg < 4; ++kg) {
      ak[kg][0] = *(const frag8*)(kb_ + offKb[0] + kg * 2048);
      ak[kg][1] = *(const frag8*)(kb_ + offKb[1] + kg * 2048);
    }
    const int k0 = kt * 64;
    const int gok[2] = {gok0, gok1};
    frag4 pk[2][4];
#pragma unroll
    for (int g = 0; g < 2; ++g) {
      if (!gok[g]) continue;
      f32x4 st[4] = {};
#pragma unroll
      for (int kg = 0; kg < 4; ++kg) {
        st[kg] = MFMA16(ak[kg][0], bq[g][0], st[kg]);
        st[kg] = MFMA16(ak[kg][1], bq[g][1], st[kg]);
      }
      if (mmode) {
#pragma unroll
        for (int kg = 0; kg < 4; ++kg) {
          float pr[4];
#pragma unroll
          for (int r = 0; r < 4; ++r) {
            int kc = k0 + kg * 16 + quad * 4 + r;
            bool act = ((u32)(kc - mlo[g]) <= mspan[g]);
            if (mmode == 2) act = act || (kc < NG);
            float e = EXP2(st[kg][r]);      // scores finite; exp issues early
            pr[r] = act ? e : 0.0f;
          }
          pk[g][kg] = pack4_bf16(pr[0], pr[1], pr[2], pr[3]);
        }
      } else {
#pragma unroll
        for (int kg = 0; kg < 4; ++kg)
          pk[g][kg] = pack4_bf16(EXP2(st[kg][0]), EXP2(st[kg][1]),
                                 EXP2(st[kg][2]), EXP2(st[kg][3]));
      }
    }
    // PV: V^T frags read once; static group indices in each branch (no
    // runtime-indexed register arrays)
    if (gok0 & gok1) {
#pragma unroll
      for (int kg = 0; kg < 4; ++kg) {
        o_l[0] = mfma_16x16x16_bf16(ones, pk[0][kg], o_l[0]);
        o_l[1] = mfma_16x16x16_bf16(ones, pk[1][kg], o_l[1]);
#pragma unroll
        for (int nt = 0; nt < 4; ++nt) {
          frag4 av = *(const frag4*)(vb_ + offVb[kg] + nt * 2048);
          o[0][nt] = mfma_16x16x16_bf16(av, pk[0][kg], o[0][nt]);
          o[1][nt] = mfma_16x16x16_bf16(av, pk[1][kg], o[1][nt]);
        }
      }
    } else if (gok0) {
#pragma unroll
      for (int kg = 0; kg < 4; ++kg) {
        o_l[0] = mfma_16x16x16_bf16(ones, pk[0][kg], o_l[0]);
#pragma unroll
        for (int nt = 0; nt < 4; ++nt) {
          frag4 av = *(const frag4*)(vb_ + offVb[kg] + nt * 2048);
          o[0][nt] = mfma_16x16x16_bf16(av, pk[0][kg], o[0][nt]);
        }
      }
    } else {
#pragma unroll
      for (int kg = 0; kg < 4; ++kg) {
        o_l[1] = mfma_16x16x16_bf16(ones, pk[1][kg], o_l[1]);
#pragma unroll
        for (int nt = 0; nt < 4; ++nt) {
          frag4 av = *(const frag4*)(vb_ + offVb[kg] + nt * 2048);
          o[1][nt] = mfma_16x16x16_bf16(av, pk[1][kg], o[1][nt]);
        }
      }
    }
  };

  if (heavy) {
    const int seg = unit & 3;
    const int kt0 = seg * 8;
    const bool dm = (strip == 1);         // q 128..255 straddles NG cutoff
    int p = 0;
    stage(kt0, 0);
#pragma unroll 1
    for (int tt = 0; tt < 8; ++tt) {
      __syncthreads();
      if (tt < 7) stage(kt0 + tt + 1, p ^ 1);
      const int kt = kt0 + tt;
      const int mm = dm ? ((kt == 3) ? 2 : ((kt > 2) ? 1 : 0)) : 0;
      step(kt, p, mm);
      p ^= 1;
    }
    // partials: Op[(bh*2+strip)*4+seg][q 0..127][d 0..63], Lp[...][q 0..127]
    float* op = Op + ((size_t)((bh * 2 + strip) * 4 + seg)) * 8192;
    float* lp = Lp + ((size_t)((bh * 2 + strip) * 4 + seg)) * 128;
#pragma unroll
    for (int g = 0; g < 2; ++g) {
      int rl = g * 64 + w * 16 + l15;
      if (quad == 0) lp[rl] = o_l[g][0];
#pragma unroll
      for (int nt = 0; nt < 4; ++nt)
        *(float4*)&op[rl * 64 + nt * 16 + quad * 4] =
            make_float4(o[g][nt][0], o[g][nt][1], o[g][nt][2], o[g][nt][3]);
    }
    return;
  }

  // light path: q0 >= 256, tile-skip loop (global cols 0..3 + window band)
  auto activef = [&](int t) {
    int k0 = t * 64;
    return (k0 < NG) || (k0 + 63 >= q0 - 64 && k0 <= q0 + 127 + 64);
  };
  auto nextt = [&](int cur) { int n = cur + 1; while (n < 32 && !activef(n)) ++n; return n; };

  int kt = 0, p = 0;                      // tile 0 always active (global cols)
  stage(0, 0);
  for (;;) {
    int ktn = nextt(kt);
    bool more = ktn < 32;
    __syncthreads();
    if (more) stage(ktn, p ^ 1);
    const int mm = (kt == 3) ? 2 : ((kt > 2) ? 1 : 0);
    step(kt, p, mm);
    if (!more) break;
    kt = ktn; p ^= 1;
  }

#pragma unroll
  for (int g = 0; g < 2; ++g) {
    float inv = 1.0f / o_l[g][0];
    u16* crow = Ctx + (size_t)((size_t)b * S_ + qw + g * 64 + l15) * DM + h * 64;
#pragma unroll
    for (int nt = 0; nt < 4; ++nt) {
      u32 lo = (u32)f2bf(o[g][nt][0] * inv) | ((u32)f2bf(o[g][nt][1] * inv) << 16);
      u32 hi = (u32)f2bf(o[g][nt][2] * inv) | ((u32)f2bf(o[g][nt][3] * inv) << 16);
      *(uint2*)&crow[nt * 16 + quad * 4] = make_uint2(lo, hi);
    }
  }
}

// ---------------- combine split-K partials -> Ctx rows 0..255 ----------------
// 128 blocks (4 strips of 64 q x 32 bh), 256 thr: row = t>>2, 16 d-cols each.
__global__ __launch_bounds__(256) void combine_kernel(const float* __restrict__ Op,
                                                      const float* __restrict__ Lp,
                                                      u16* __restrict__ Ctx) {
  const int blk = blockIdx.x;
  const int bh = blk & 31, s64 = blk >> 5;      // 64-row strip 0..3
  const int b = bh >> 4, h = bh & 15;
  const int t = threadIdx.x;
  const int row = t >> 2, colg = (t & 3) * 16;
  const int gq = s64 * 64 + row;                 // 0..255
  const int strip = gq >> 7, rIn = gq & 127;     // 128-row partial index

  const float* opb = Op + ((size_t)(bh * 2 + strip) * 4) * 8192;
  const float* lpb = Lp + ((size_t)(bh * 2 + strip) * 4) * 128;

  float l = lpb[rIn] + lpb[128 + rIn] + lpb[256 + rIn] + lpb[384 + rIn];
  float acc[16];
#pragma unroll
  for (int e = 0; e < 16; ++e) acc[e] = opb[rIn * 64 + colg + e];
#pragma unroll
  for (int seg = 1; seg < 4; ++seg)
#pragma unroll
    for (int e = 0; e < 16; ++e) acc[e] += opb[seg * 8192 + rIn * 64 + colg + e];

  float inv = 1.0f / l;
  u32 pk[8];
#pragma unroll
  for (int p = 0; p < 8; ++p)
    pk[p] = (u32)f2bf(acc[2 * p] * inv) | ((u32)f2bf(acc[2 * p + 1] * inv) << 16);
  u16* dst = Ctx + (size_t)((size_t)b * S_ + gq) * DM + h * 64 + colg;
  *(uint4*)dst       = make_uint4(pk[0], pk[1], pk[2], pk[3]);
  *(uint4*)(dst + 8) = make_uint4(pk[4], pk[5], pk[6], pk[7]);
}

// ---------------- launch ----------------
extern "C" void kernel_launch(void* const* d_in, const int* in_sizes, int n_in,
                              void* d_out, int out_size, void* d_ws, size_t ws_size,
                              hipStream_t stream) {
  const float* X  = (const float*)d_in[0];
  const float* Wq = (const float*)d_in[1];
  const float* bq = (const float*)d_in[2];
  const float* Wk = (const float*)d_in[3];
  const float* bk = (const float*)d_in[4];
  const float* Wv = (const float*)d_in[5];
  const float* bv = (const float*)d_in[6];
  const float* Wo = (const float*)d_in[7];
  const float* bo = (const float*)d_in[8];
  float* out = (float*)d_out;

  u16* ws = (u16*)d_ws;
  const size_t NX = (size_t)BS_ * DM;
  const size_t NW = (size_t)DM * DM;
  u16* Xb  = ws;
  u16* Wqb = Xb + NX;
  u16* Wkb = Wqb + NW;
  u16* Wvb = Wkb + NW;
  u16* Wob = Wvb + NW;
  u16* Qb  = Wob + NW;
  u16* Kb  = Qb + NX;
  u16* Vt  = Kb + NX;
  u16* Cx  = Vt + NX;
  float* Op = (float*)(Cx + NX);               // 32*2*4*8192 = 2.1M floats (8 MB)
  float* Lp = Op + (size_t)32 * 2 * 4 * 8192;  // 32k floats

  cvt_all<<<dim3(1024, 8), 256, 0, stream>>>(X, Wq, Wk, Wv, Wo, Xb, Wqb, Wkb, Wvb, Wob);
  gemm_qkv<<<dim3(24, 32), 256, 0, stream>>>(Xb, Wqb, Wkb, Wvb, bq, bk, bv, Qb, Kb, Vt);
  attn_kernel<<<22 * 32, 256, 0, stream>>>(Qb, Kb, Vt, Cx, Op, Lp);
  combine_kernel<<<128, 256, 0, stream>>>(Op, Lp, Cx);
  gemm_wo<<<dim3(8, 32), 256, 0, stream>>>(Cx, Wob, bo, out);
}